// Round 15
// baseline (319.076 us; speedup 1.0000x reference)
//
#include <hip/hip_runtime.h>
#include <hip/hip_bf16.h>

// ============================================================================
// GAT 2-layer forward, round 15.
// r14 post-mortem: seg kernels pinned at ~56us across 3 structurally
// different inner loops, VALUBusy ~54%, no pipe saturated, ~120us of total
// unaccounted => per-workgroup dispatch/retire overhead of 25000 tiny blocks
// (~64 edges each) is the floor.
// Fix: 32 dst nodes per seg block (8 groups x 4 nodes, group loop around the
// r14 body) -> 3125 blocks. k_init folded into hipMemsetAsync (gcur=offsets).
// Facts: fp32 in/out, int32 edge_index, N=100000 E=1600000, bf16 h.
// ============================================================================

typedef __hip_bfloat16 bf16;
typedef unsigned short ushort;
typedef unsigned char uchar;
typedef __attribute__((ext_vector_type(8))) short short8;
typedef __attribute__((ext_vector_type(4))) float f32x4;

#define NN 100000
#define EE 1600000
#define CH 256
#define BKB 9
#define BKN (1 << BKB)
#define NBK ((NN + BKN - 1) >> BKB)   // 196
#define CAP 10240                     // arena slots per bucket (max ~8.5K)
#define TILE 4096
#define EPT 16
#define NT ((EE + TILE - 1) / TILE)
#define NPB 32                        // dst nodes per seg block (8 groups of 4)

__device__ __forceinline__ float relu_np(float v) { return (v < 0.f) ? 0.f : v; }
__device__ __forceinline__ float lrelu(float v) { return v > 0.f ? v : 0.2f * v; }
__device__ __forceinline__ ushort f2bf(float f) {
    __hip_bfloat16 h = __float2bfloat16(f);
    return *reinterpret_cast<ushort*>(&h);
}
__device__ __forceinline__ float bf2f(ushort u) {
    unsigned int x = ((unsigned int)u) << 16;
    return __uint_as_float(x);
}

// ---- partition into per-bucket arenas (block-aggregated writes) ------------
// gcur[b] holds the FILL LEVEL (offset from b*CAP); memset-0 initialized.
__global__ __launch_bounds__(256) void k_part(
    const int* __restrict__ src, const int* __restrict__ dst,
    int* __restrict__ gcur, int* __restrict__ pairs, int E)
{
    __shared__ int lh[NBK];
    __shared__ int lbase[NBK];
    const int tid = threadIdx.x;
    for (int i = tid; i < NBK; i += 256) lh[i] = 0;
    __syncthreads();
    const int e0 = blockIdx.x * TILE;
    int pk[EPT], bk[EPT], rv[EPT];
    #pragma unroll
    for (int j = 0; j < EPT; ++j) {
        int e = e0 + j * 256 + tid;
        if (e < E) {
            int d = dst[e];
            bk[j] = d >> BKB;
            pk[j] = src[e] | ((d & (BKN - 1)) << 17);
            rv[j] = atomicAdd(&lh[bk[j]], 1);
        }
    }
    __syncthreads();
    for (int i = tid; i < NBK; i += 256)
        lbase[i] = lh[i] ? (i * CAP + atomicAdd(&gcur[i], lh[i])) : 0;
    __syncthreads();
    #pragma unroll
    for (int j = 0; j < EPT; ++j) {
        int e = e0 + j * 256 + tid;
        if (e < E) pairs[lbase[bk[j]] + rv[j]] = pk[j];
    }
}

// ---- per-bucket: node hist + scan -> row_ptr + rcnt; scatter col -----------
__global__ __launch_bounds__(256) void k_bucket(
    const int* __restrict__ gcur, const int* __restrict__ pairs,
    int* __restrict__ row_ptr, uchar* __restrict__ rcnt,
    int* __restrict__ col, int N)
{
    __shared__ int hist[BKN];
    __shared__ int sP[256];
    const int b = blockIdx.x;
    const int n0 = b << BKB;
    const int tid = threadIdx.x;
    const int base = b * CAP, endE = base + gcur[b];
    for (int i = tid; i < BKN; i += 256) hist[i] = 0;
    __syncthreads();
    for (int i = base + tid; i < endE; i += 256)
        atomicAdd(&hist[pairs[i] >> 17], 1);
    __syncthreads();
    int a0 = hist[2 * tid], a1 = hist[2 * tid + 1];
    int tot = a0 + a1;
    sP[tid] = tot;
    __syncthreads();
    for (int off = 1; off < 256; off <<= 1) {
        int t = (tid >= off) ? sP[tid - off] : 0;
        __syncthreads();
        sP[tid] += t;
        __syncthreads();
    }
    const int excl = sP[tid] - tot;
    const int c0 = base + excl;
    hist[2 * tid] = c0;
    hist[2 * tid + 1] = c0 + a0;
    if (n0 + 2 * tid < N) {
        row_ptr[n0 + 2 * tid] = c0;
        rcnt[n0 + 2 * tid] = (uchar)a0;
    }
    if (n0 + 2 * tid + 1 < N) {
        row_ptr[n0 + 2 * tid + 1] = c0 + a0;
        rcnt[n0 + 2 * tid + 1] = (uchar)a1;
    }
    __syncthreads();
    for (int i = base + tid; i < endE; i += 256) {
        int pr = pairs[i];
        int p = atomicAdd(&hist[pr >> 17], 1);
        col[p] = pr & 0x1FFFF;
    }
}

// ---------------- GEMM1 (MFMA) with alpha as extra B columns -----------------
__global__ __launch_bounds__(256) void k_gemm1(
    const float* __restrict__ x, const float* __restrict__ W1,
    const float* __restrict__ aS, const float* __restrict__ aD,
    ushort* __restrict__ h1, float* __restrict__ as1, float* __restrict__ ad1,
    int N)
{
    __shared__ ushort wB[64 * 128];
    __shared__ ushort wE[16 * 128];
    const int tid = threadIdx.x;
    for (int i = tid; i < 128 * 64; i += 256) {
        int k = i >> 6, n = i & 63;
        wB[n * 128 + k] = f2bf(W1[i]);
    }
    for (int i = tid; i < 128 * 16; i += 256) {
        int k = i >> 4, j = i & 15;
        float v = 0.f;
        if (j < 8) {
            int h = j & 3;
            const float* av = (j < 4) ? aS : aD;
            for (int c = 0; c < 16; ++c)
                v = fmaf(W1[k * 64 + h * 16 + c], av[h * 16 + c], v);
        }
        wE[j * 128 + k] = f2bf(v);
    }
    __syncthreads();
    const int w = tid >> 6, lane = tid & 63;
    const int m = lane & 15, quad = lane >> 4;
    const int ntiles = N >> 4;
    for (int tile = blockIdx.x * 4 + w; tile < ntiles; tile += gridDim.x * 4) {
        const int row0 = tile << 4;
        f32x4 acc[4] = {f32x4{0,0,0,0}, f32x4{0,0,0,0},
                        f32x4{0,0,0,0}, f32x4{0,0,0,0}};
        f32x4 acc5 = {0, 0, 0, 0};
        const float* xp = x + (size_t)(row0 + m) * 128 + quad * 8;
        #pragma unroll
        for (int ks = 0; ks < 128; ks += 32) {
            f32x4 x0 = *(const f32x4*)(xp + ks);
            f32x4 x1 = *(const f32x4*)(xp + ks + 4);
            short8 a;
            #pragma unroll
            for (int j = 0; j < 4; ++j) a[j] = (short)f2bf(x0[j]);
            #pragma unroll
            for (int j = 0; j < 4; ++j) a[4 + j] = (short)f2bf(x1[j]);
            #pragma unroll
            for (int t = 0; t < 4; ++t) {
                short8 b = *(const short8*)&wB[(t * 16 + m) * 128 + ks + quad * 8];
                acc[t] = __builtin_amdgcn_mfma_f32_16x16x32_bf16(a, b, acc[t], 0, 0, 0);
            }
            short8 b5 = *(const short8*)&wE[m * 128 + ks + quad * 8];
            acc5 = __builtin_amdgcn_mfma_f32_16x16x32_bf16(a, b5, acc5, 0, 0, 0);
        }
        #pragma unroll
        for (int t = 0; t < 4; ++t)
            #pragma unroll
            for (int r = 0; r < 4; ++r)
                h1[(size_t)(row0 + quad * 4 + r) * 64 + t * 16 + m] = f2bf(acc[t][r]);
        #pragma unroll
        for (int r = 0; r < 4; ++r) {
            int row = row0 + quad * 4 + r;
            if (m < 4) as1[row * 4 + m] = acc5[r];
            else if (m < 8) ad1[row * 4 + (m - 4)] = acc5[r];
        }
    }
}

// ---------------- GEMM2 (MFMA) with alpha ext cols ---------------------------
__global__ __launch_bounds__(256) void k_gemm2(
    const float* __restrict__ in, const float* __restrict__ b1,
    const float* __restrict__ W2,
    const float* __restrict__ aS, const float* __restrict__ aD,
    ushort* __restrict__ h2, float* __restrict__ as2, float* __restrict__ ad2,
    int N)
{
    __shared__ ushort wB[64 * 64];
    __shared__ ushort wE[16 * 64];
    __shared__ float bS[64];
    const int tid = threadIdx.x;
    for (int i = tid; i < 64 * 64; i += 256) {
        int k = i >> 6, n = i & 63;
        wB[n * 64 + k] = f2bf(W2[i]);
    }
    for (int i = tid; i < 64 * 16; i += 256) {
        int k = i >> 4, j = i & 15;
        float v = 0.f;
        if (j < 2) {
            const float* av = (j == 0) ? aS : aD;
            for (int c = 0; c < 64; ++c)
                v = fmaf(W2[k * 64 + c], av[c], v);
        }
        wE[j * 64 + k] = f2bf(v);
    }
    if (tid < 64) bS[tid] = b1[tid];
    __syncthreads();
    const int w = tid >> 6, lane = tid & 63;
    const int m = lane & 15, quad = lane >> 4;
    const int ntiles = N >> 4;
    for (int tile = blockIdx.x * 4 + w; tile < ntiles; tile += gridDim.x * 4) {
        const int row0 = tile << 4;
        f32x4 acc[4] = {f32x4{0,0,0,0}, f32x4{0,0,0,0},
                        f32x4{0,0,0,0}, f32x4{0,0,0,0}};
        f32x4 acc5 = {0, 0, 0, 0};
        const float* ip = in + (size_t)(row0 + m) * 64 + quad * 8;
        #pragma unroll
        for (int ks = 0; ks < 64; ks += 32) {
            short8 a;
            #pragma unroll
            for (int j = 0; j < 8; ++j)
                a[j] = (short)f2bf(relu_np(ip[ks + j] + bS[ks + quad * 8 + j]));
            #pragma unroll
            for (int t = 0; t < 4; ++t) {
                short8 b = *(const short8*)&wB[(t * 16 + m) * 64 + ks + quad * 8];
                acc[t] = __builtin_amdgcn_mfma_f32_16x16x32_bf16(a, b, acc[t], 0, 0, 0);
            }
            short8 b5 = *(const short8*)&wE[m * 64 + ks + quad * 8];
            acc5 = __builtin_amdgcn_mfma_f32_16x16x32_bf16(a, b5, acc5, 0, 0, 0);
        }
        #pragma unroll
        for (int t = 0; t < 4; ++t)
            #pragma unroll
            for (int r = 0; r < 4; ++r)
                h2[(size_t)(row0 + quad * 4 + r) * 64 + t * 16 + m] = f2bf(acc[t][r]);
        #pragma unroll
        for (int r = 0; r < 4; ++r) {
            int row = row0 + quad * 4 + r;
            if (m == 0) as2[row] = acc5[r];
            else if (m == 1) ad2[row] = acc5[r];
        }
    }
}

// ---------------- layer-1 segment aggregation (32 nodes/block) ---------------
__global__ __launch_bounds__(256) void k_seg1(
    const int* __restrict__ rp, const uchar* __restrict__ rcnt,
    const int* __restrict__ col,
    const float* __restrict__ as1, const float* __restrict__ ad1,
    const ushort* __restrict__ h1, float* __restrict__ out, int N)
{
    __shared__ float pS[CH * 4];
    __shared__ int colS[CH];
    __shared__ int sRp[NPB];
    __shared__ int sCnt[NPB];
    const int tid = threadIdx.x;
    const int n0 = blockIdx.x * NPB;     // N % 32 == 0; blocks never straddle buckets
    if (tid < NPB) {
        sRp[tid] = rp[n0 + tid];
        sCnt[tid] = rcnt[n0 + tid];
    }
    __syncthreads();
    const int w = tid >> 6, lane = tid & 63;
    const int slot = lane >> 4, c4 = lane & 15, head = c4 >> 2;
    const int uid = slot * 4 + (c4 & 3);

    for (int g = 0; g < NPB / 4; ++g) {
        const int gb = g * 4;
        const int eb0 = sRp[gb], eb4 = sRp[gb + 3] + sCnt[gb + 3];
        const int myn = n0 + gb + w;
        const int s_n = sRp[gb + w], e_n = s_n + sCnt[gb + w];

        float den = 0.f;
        f32x4 accA = {0,0,0,0}, accB = {0,0,0,0};

        for (int base = eb0; base < eb4; base += CH) {
            const int cnt = min(CH, eb4 - base);
            __syncthreads();
            for (int t = tid; t < cnt; t += 256) colS[t] = col[base + t];
            __syncthreads();
            for (int t = tid; t < cnt * 4; t += 256) {
                int e = t >> 2, hh = t & 3;
                int ge = base + e;
                int nd = n0 + gb + (ge >= sRp[gb + 1]) + (ge >= sRp[gb + 2])
                       + (ge >= sRp[gb + 3]);
                float v = as1[(size_t)colS[e] * 4 + hh] + ad1[(size_t)nd * 4 + hh];
                pS[t] = __expf(lrelu(v));
            }
            __syncthreads();

            const int lo = max(s_n, base), hi = min(e_n, base + cnt);
            for (int i = lo + uid; i < hi; i += 16)
                den += pS[(i - base) * 4 + head];
            int i = lo;
            for (; i + 7 < hi; i += 8) {
                int lA = i - base + slot, lB = lA + 4;
                float pA = pS[lA * 4 + head], pB = pS[lB * 4 + head];
                ushort4 hA = *(const ushort4*)&h1[(size_t)colS[lA] * 64 + c4 * 4];
                ushort4 hB = *(const ushort4*)&h1[(size_t)colS[lB] * 64 + c4 * 4];
                accA[0] = fmaf(pA, bf2f(hA.x), accA[0]);
                accA[1] = fmaf(pA, bf2f(hA.y), accA[1]);
                accA[2] = fmaf(pA, bf2f(hA.z), accA[2]);
                accA[3] = fmaf(pA, bf2f(hA.w), accA[3]);
                accB[0] = fmaf(pB, bf2f(hB.x), accB[0]);
                accB[1] = fmaf(pB, bf2f(hB.y), accB[1]);
                accB[2] = fmaf(pB, bf2f(hB.z), accB[2]);
                accB[3] = fmaf(pB, bf2f(hB.w), accB[3]);
            }
            for (; i < hi; i += 4) {
                int ii = i + slot;
                if (ii < hi) {
                    int li = ii - base;
                    float p = pS[li * 4 + head];
                    ushort4 hv = *(const ushort4*)&h1[(size_t)colS[li] * 64 + c4 * 4];
                    accA[0] = fmaf(p, bf2f(hv.x), accA[0]);
                    accA[1] = fmaf(p, bf2f(hv.y), accA[1]);
                    accA[2] = fmaf(p, bf2f(hv.z), accA[2]);
                    accA[3] = fmaf(p, bf2f(hv.w), accA[3]);
                }
            }
        }
        den += __shfl_xor(den, 1);
        den += __shfl_xor(den, 2);
        den += __shfl_xor(den, 16);
        den += __shfl_xor(den, 32);
        #pragma unroll
        for (int j = 0; j < 4; ++j) {
            accA[j] += accB[j];
            accA[j] += __shfl_xor(accA[j], 16);
            accA[j] += __shfl_xor(accA[j], 32);
        }
        if (myn < N && slot == 0) {
            float inv = 1.f / (den + 1e-16f);
            f32x4 o = {accA[0] * inv, accA[1] * inv, accA[2] * inv, accA[3] * inv};
            *(f32x4*)&out[(size_t)myn * 64 + c4 * 4] = o;
        }
    }
}

// ---------------- layer-2 segment aggregation + fused classifier head -------
__global__ __launch_bounds__(256) void k_seg2(
    const int* __restrict__ rp, const uchar* __restrict__ rcnt,
    const int* __restrict__ col,
    const float* __restrict__ as2, const float* __restrict__ ad2,
    const ushort* __restrict__ h2, const float* __restrict__ b2,
    const float* __restrict__ Wc, const float* __restrict__ bc,
    float* __restrict__ out, int N)
{
    __shared__ float pS[CH];
    __shared__ int colS[CH];
    __shared__ int sRp[NPB];
    __shared__ int sCnt[NPB];
    const int tid = threadIdx.x;
    const int n0 = blockIdx.x * NPB;
    if (tid < NPB) {
        sRp[tid] = rp[n0 + tid];
        sCnt[tid] = rcnt[n0 + tid];
    }
    __syncthreads();
    const int w = tid >> 6, lane = tid & 63;
    const int slot = lane >> 4, c4 = lane & 15;

    for (int g = 0; g < NPB / 4; ++g) {
        const int gb = g * 4;
        const int eb0 = sRp[gb], eb4 = sRp[gb + 3] + sCnt[gb + 3];
        const int myn = n0 + gb + w;
        const int s_n = sRp[gb + w], e_n = s_n + sCnt[gb + w];

        float den = 0.f;
        f32x4 accA = {0,0,0,0}, accB = {0,0,0,0};

        for (int base = eb0; base < eb4; base += CH) {
            const int cnt = min(CH, eb4 - base);
            __syncthreads();
            for (int t = tid; t < cnt; t += 256) colS[t] = col[base + t];
            __syncthreads();
            for (int t = tid; t < cnt; t += 256) {
                int ge = base + t;
                int nd = n0 + gb + (ge >= sRp[gb + 1]) + (ge >= sRp[gb + 2])
                       + (ge >= sRp[gb + 3]);
                pS[t] = __expf(lrelu(as2[colS[t]] + ad2[nd]));
            }
            __syncthreads();

            const int lo = max(s_n, base), hi = min(e_n, base + cnt);
            for (int i = lo + lane; i < hi; i += 64) den += pS[i - base];
            int i = lo;
            for (; i + 7 < hi; i += 8) {
                int lA = i - base + slot, lB = lA + 4;
                float pA = pS[lA], pB = pS[lB];
                ushort4 hA = *(const ushort4*)&h2[(size_t)colS[lA] * 64 + c4 * 4];
                ushort4 hB = *(const ushort4*)&h2[(size_t)colS[lB] * 64 + c4 * 4];
                accA[0] = fmaf(pA, bf2f(hA.x), accA[0]);
                accA[1] = fmaf(pA, bf2f(hA.y), accA[1]);
                accA[2] = fmaf(pA, bf2f(hA.z), accA[2]);
                accA[3] = fmaf(pA, bf2f(hA.w), accA[3]);
                accB[0] = fmaf(pB, bf2f(hB.x), accB[0]);
                accB[1] = fmaf(pB, bf2f(hB.y), accB[1]);
                accB[2] = fmaf(pB, bf2f(hB.z), accB[2]);
                accB[3] = fmaf(pB, bf2f(hB.w), accB[3]);
            }
            for (; i < hi; i += 4) {
                int ii = i + slot;
                if (ii < hi) {
                    int li = ii - base;
                    float p = pS[li];
                    ushort4 hv = *(const ushort4*)&h2[(size_t)colS[li] * 64 + c4 * 4];
                    accA[0] = fmaf(p, bf2f(hv.x), accA[0]);
                    accA[1] = fmaf(p, bf2f(hv.y), accA[1]);
                    accA[2] = fmaf(p, bf2f(hv.z), accA[2]);
                    accA[3] = fmaf(p, bf2f(hv.w), accA[3]);
                }
            }
        }
        #pragma unroll
        for (int off = 32; off >= 1; off >>= 1) den += __shfl_xor(den, off);
        #pragma unroll
        for (int j = 0; j < 4; ++j) {
            accA[j] += accB[j];
            accA[j] += __shfl_xor(accA[j], 16);
            accA[j] += __shfl_xor(accA[j], 32);
        }
        if (myn < N && slot == 0) {
            float inv = 1.f / (den + 1e-16f);
            const f32x4 b4 = *(const f32x4*)&b2[c4 * 4];
            const f32x4 w4 = *(const f32x4*)&Wc[c4 * 4];
            float t = 0.f;
            #pragma unroll
            for (int j = 0; j < 4; ++j)
                t += relu_np(accA[j] * inv + b4[j]) * w4[j];
            t += __shfl_xor(t, 1);
            t += __shfl_xor(t, 2);
            t += __shfl_xor(t, 4);
            t += __shfl_xor(t, 8);
            if (c4 == 0) out[myn] = t + bc[0];
        }
    }
}

extern "C" void kernel_launch(void* const* d_in, const int* in_sizes, int n_in,
                              void* d_out, int out_size, void* d_ws, size_t ws_size,
                              hipStream_t stream)
{
    const float* x   = (const float*)d_in[0];
    const int*   ei  = (const int*)d_in[1];
    const float* W1  = (const float*)d_in[2];
    const float* aS1 = (const float*)d_in[3];
    const float* aD1 = (const float*)d_in[4];
    const float* b1  = (const float*)d_in[5];
    const float* W2  = (const float*)d_in[6];
    const float* aS2 = (const float*)d_in[7];
    const float* aD2 = (const float*)d_in[8];
    const float* b2  = (const float*)d_in[9];
    const float* Wc  = (const float*)d_in[10];
    const float* bc  = (const float*)d_in[11];
    float* out = (float*)d_out;

    const int N = NN;
    const int E = EE;
    const int* src = ei;
    const int* dst = ei + E;

    float* w = (float*)d_ws;
    ushort* hB   = (ushort*)w;                        // bf16 h1/h2 [N*64] 12.8MB
    float* bufO  = w + (size_t)N * 32;                // out1 fp32 [N*64] 25.6MB
    float* as1   = bufO + (size_t)N * 64;             // [4N]
    float* ad1   = as1 + (size_t)N * 4;               // [4N]
    float* as2   = ad1 + (size_t)N * 4;               // [N]
    float* ad2   = as2 + (size_t)N;                   // [N]
    int* row_ptr = (int*)(ad2 + (size_t)N);           // [N]
    uchar* rcnt  = (uchar*)(row_ptr + N);             // [N] bytes
    int* gcur    = (int*)(rcnt + ((N + 3) & ~3));     // [NBK]
    int* col     = gcur + NBK;                        // [NBK*CAP] 8MB arena
    int* pairs   = (int*)bufO;                        // [NBK*CAP] aliases bufO

    // ---- CSR build: zero cursors -> arena partition -> per-bucket order ----
    hipMemsetAsync(gcur, 0, NBK * sizeof(int), stream);
    k_part<<<NT, 256, 0, stream>>>(src, dst, gcur, pairs, E);
    k_bucket<<<NBK, 256, 0, stream>>>(gcur, pairs, row_ptr, rcnt, col, N);

    // ---- layer 1 ----
    k_gemm1<<<782, 256, 0, stream>>>(x, W1, aS1, aD1, hB, as1, ad1, N);
    k_seg1<<<(N + NPB - 1) / NPB, 256, 0, stream>>>(row_ptr, rcnt, col,
                                                    as1, ad1, hB, bufO, N);

    // ---- layer 2 ----
    k_gemm2<<<782, 256, 0, stream>>>(bufO, b1, W2, aS2, aD2, hB, as2, ad2, N);
    k_seg2<<<(N + NPB - 1) / NPB, 256, 0, stream>>>(row_ptr, rcnt, col,
                                                    as2, ad2, hB, b2, Wc, bc, out, N);
}